// Round 10
// baseline (259.967 us; speedup 1.0000x reference)
//
#include <hip/hip_runtime.h>
#include <hip/hip_bf16.h>

constexpr int BATCH = 256, NNODE = 512, WINW = 64, EMBD = 64, KTOP = 16, CIN = 512;
constexpr int NTOT = BATCH * NNODE;          // 131072
constexpr float NEGS = 0.2f;
constexpr float EPSBN = 1e-5f;
constexpr int XLP = 68;                      // LDS pitch for xl (2-way banks)

typedef __attribute__((ext_vector_type(8))) short bf16x8;
typedef __attribute__((ext_vector_type(4))) float f32x4;

union U8 { uint4 u; bf16x8 b; };

__device__ inline float bf2f(unsigned u16) {
  union { unsigned u; float f; } v; v.u = u16 << 16; return v.f;
}
// packed fp32x2 -> bf16x2 (v_cvt_pk_bf16_f32), a in low half
__device__ inline unsigned pkbf(float a, float b) {
  __hip_bfloat162 h = __float22bfloat162_rn(make_float2(a, b));
  return *(unsigned*)&h;
}

// ---- K0: normalize embeddings + per-node attention-embedding dots ----------
__global__ void k_prep(const float* __restrict__ W_emb,
                       const float* __restrict__ att_em_i,
                       const float* __restrict__ att_em_j,
                       float* __restrict__ nw, float* __restrict__ emb_si,
                       float* __restrict__ emb_sj) {
  int i = blockIdx.x, e = threadIdx.x;   // block = 64 threads
  float w  = W_emb[i * EMBD + e];
  float sq = w * w;
  float si = w * att_em_i[e];
  float sj = w * att_em_j[e];
  for (int o = 32; o > 0; o >>= 1) {
    sq += __shfl_xor(sq, o);
    si += __shfl_xor(si, o);
    sj += __shfl_xor(sj, o);
  }
  nw[i * EMBD + e] = w * rsqrtf(sq);
  if (e == 0) { emb_si[i] = si; emb_sj[i] = sj; }
}

// ---- K1: cosine top-16 per node — shuffle argmax ---------------------------
__global__ __launch_bounds__(256) void k_topk(const float* __restrict__ nw,
                                              int* __restrict__ topk) {
  __shared__ float nwi[EMBD];
  __shared__ float wbv[4];
  __shared__ int   wbi[4];
  __shared__ int   winner;
  int i = blockIdx.x, t = threadIdx.x, wv = t >> 6, ln = t & 63;
  if (t < EMBD) nwi[t] = nw[i * EMBD + t];
  __syncthreads();
  float v0 = 0.f, v1 = 0.f;
  #pragma unroll
  for (int k = 0; k < EMBD; k++) {
    v0 += nw[t * EMBD + k] * nwi[k];
    v1 += nw[(t + 256) * EMBD + k] * nwi[k];
  }
  for (int sel = 0; sel < KTOP; sel++) {
    float bv; int bi;
    if (v1 > v0) { bv = v1; bi = t + 256; } else { bv = v0; bi = t; }  // tie -> lower idx
    #pragma unroll
    for (int o = 1; o < 64; o <<= 1) {
      float ov = __shfl_xor(bv, o);
      int   oi = __shfl_xor(bi, o);
      if (ov > bv || (ov == bv && oi < bi)) { bv = ov; bi = oi; }
    }
    if (ln == 0) { wbv[wv] = bv; wbi[wv] = bi; }
    __syncthreads();
    if (t == 0) {
      float B = wbv[0]; int I = wbi[0];
      #pragma unroll
      for (int w = 1; w < 4; w++)
        if (wbv[w] > B || (wbv[w] == B && wbi[w] < I)) { B = wbv[w]; I = wbi[w]; }
      topk[i * KTOP + sel] = I;
      winner = I;
    }
    __syncthreads();
    int wi = winner;
    if (wi == t) v0 = -3.f;
    else if (wi == t + 256) v1 = -3.f;
  }
}

// ============================================================================
// K_FUSE4: one block per batch (grid=256, 1024 thr = 16 waves).
// Phase A: xl = x @ W_lin^T via bf16 MFMA -> LDS fp32 (pitch 68). Phase B:
// lane-parallel softmax (1 exp/lane, shuffle reductions + weight broadcast),
// agg -> global bf16 + BN1 stats.
// ============================================================================
__global__ __launch_bounds__(1024) void k_fuse4(
    const float* __restrict__ data, const float* __restrict__ W_lin,
    const float* __restrict__ att_i, const float* __restrict__ att_j,
    const float* __restrict__ emb_si, const float* __restrict__ emb_sj,
    const int* __restrict__ topk,
    unsigned* __restrict__ aggb, float* __restrict__ gsum1,
    float* __restrict__ gss1) {
  __shared__ float xl[NNODE * XLP];       // 136 KB
  __shared__ float ssi[NNODE];            // 2 KB
  __shared__ float ssj[NNODE];            // 2 KB
  __shared__ float redb[16 * 128];        // 8 KB
  const int b = blockIdx.x;
  const int t = threadIdx.x, w = t >> 6, ln = t & 63;
  const int lm = ln & 15, lq = ln >> 4, kb = lq * 8;

  bf16x8 bfrag[4][2];
  float ai4[4], aj4[4];
  #pragma unroll
  for (int ti = 0; ti < 4; ti++) {
    int ch = ti * 16 + lm;
    ai4[ti] = att_i[ch]; aj4[ti] = att_j[ch];
    #pragma unroll
    for (int s = 0; s < 2; s++) {
      const float* wp = W_lin + ch * WINW + s * 32 + kb;
      float4 w0 = *(const float4*)wp;
      float4 w1 = *(const float4*)(wp + 4);
      U8 f;
      f.u = make_uint4(pkbf(w0.x, w0.y), pkbf(w0.z, w0.w),
                       pkbf(w1.x, w1.y), pkbf(w1.z, w1.w));
      bfrag[ti][s] = f.b;
    }
  }
  // ---- phase A ----
  #pragma unroll
  for (int tt = 0; tt < 2; tt++) {
    int tile = w * 2 + tt;
    const float* dr = data + ((size_t)b * NNODE + tile * 16 + lm) * WINW + kb;
    f32x4 acc[4];
    #pragma unroll
    for (int ti = 0; ti < 4; ti++) acc[ti] = (f32x4){0.f, 0.f, 0.f, 0.f};
    #pragma unroll
    for (int s = 0; s < 2; s++) {
      float4 d0 = *(const float4*)(dr + s * 32);
      float4 d1 = *(const float4*)(dr + s * 32 + 4);
      U8 af;
      af.u = make_uint4(pkbf(d0.x, d0.y), pkbf(d0.z, d0.w),
                        pkbf(d1.x, d1.y), pkbf(d1.z, d1.w));
      #pragma unroll
      for (int ti = 0; ti < 4; ti++)
        acc[ti] = __builtin_amdgcn_mfma_f32_16x16x32_bf16(af.b, bfrag[ti][s], acc[ti], 0, 0, 0);
    }
    #pragma unroll
    for (int r = 0; r < 4; r++) {
      int nd = tile * 16 + lq * 4 + r;
      float si = 0.f, sj = 0.f;
      #pragma unroll
      for (int ti = 0; ti < 4; ti++) {
        float v = acc[ti][r];
        xl[nd * XLP + ti * 16 + lm] = v;
        si += v * ai4[ti];
        sj += v * aj4[ti];
      }
      si += __shfl_xor(si, 1); si += __shfl_xor(si, 2);
      si += __shfl_xor(si, 4); si += __shfl_xor(si, 8);
      sj += __shfl_xor(sj, 1); sj += __shfl_xor(sj, 2);
      sj += __shfl_xor(sj, 4); sj += __shfl_xor(sj, 8);
      if (lm == 0) { ssi[nd] = si + emb_si[nd]; ssj[nd] = sj + emb_sj[nd]; }
    }
  }
  __syncthreads();
  // ---- phase B: 4 dst nodes per wave-pass; lane = (nd4, l4) ----
  // softmax: lane l4 owns neighbor l4 (1 exp/lane), group shuffle reductions;
  // gather: weight k broadcast via __shfl from lane base+k, scale by inv once.
  const int nd4 = ln >> 4, l4 = ln & 15;
  const int lbase = ln & 48;              // nd4*16
  float psx = 0.f, psy = 0.f, psz = 0.f, psw = 0.f;
  float qsx = 0.f, qsy = 0.f, qsz = 0.f, qsw = 0.f;
  for (int it = 0; it < 8; it++) {
    int node = w * 32 + it * 4 + nd4;
    const int4* tp = (const int4*)(topk + node * KTOP);
    int4 i0 = tp[0], i1 = tp[1], i2 = tp[2], i3 = tp[3];
    int idx[16] = {i0.x, i0.y, i0.z, i0.w, i1.x, i1.y, i1.z, i1.w,
                   i2.x, i2.y, i2.z, i2.w, i3.x, i3.y, i3.z, i3.w};
    float a = ssi[node] + ssj[idx[l4]];
    a = a > 0.f ? a : NEGS * a;           // leaky_relu
    float mx = a;
    mx = fmaxf(mx, __shfl_xor(mx, 1));
    mx = fmaxf(mx, __shfl_xor(mx, 2));
    mx = fmaxf(mx, __shfl_xor(mx, 4));
    mx = fmaxf(mx, __shfl_xor(mx, 8));
    float e = __expf(a - mx);
    float den = e;
    den += __shfl_xor(den, 1); den += __shfl_xor(den, 2);
    den += __shfl_xor(den, 4); den += __shfl_xor(den, 8);
    float inv = 1.f / den;                // group-uniform
    float ax = 0.f, ay = 0.f, az = 0.f, aw = 0.f;
    #pragma unroll
    for (int k = 0; k < KTOP; k++) {
      float wk = __shfl(e, lbase + k);
      float4 v = *(const float4*)&xl[idx[k] * XLP + l4 * 4];
      ax += wk * v.x; ay += wk * v.y; az += wk * v.z; aw += wk * v.w;
    }
    ax *= inv; ay *= inv; az *= inv; aw *= inv;
    uint2 st = make_uint2(pkbf(ax, ay), pkbf(az, aw));
    *(uint2*)(aggb + (((size_t)b * NNODE + node) << 5) + l4 * 2) = st;
    psx += ax; psy += ay; psz += az; psw += aw;
    qsx += ax * ax; qsy += ay * ay; qsz += az * az; qsw += aw * aw;
  }
  #pragma unroll
  for (int o = 16; o <= 32; o <<= 1) {
    psx += __shfl_xor(psx, o); psy += __shfl_xor(psy, o);
    psz += __shfl_xor(psz, o); psw += __shfl_xor(psw, o);
    qsx += __shfl_xor(qsx, o); qsy += __shfl_xor(qsy, o);
    qsz += __shfl_xor(qsz, o); qsw += __shfl_xor(qsw, o);
  }
  if (ln < 16) {
    float4 a = {psx, psy, psz, psw};
    float4 q = {qsx, qsy, qsz, qsw};
    *(float4*)&redb[w * 128 + ln * 4] = a;
    *(float4*)&redb[w * 128 + 64 + ln * 4] = q;
  }
  __syncthreads();
  if (t < 64) {
    float s = 0.f;
    #pragma unroll
    for (int w16 = 0; w16 < 16; w16++) s += redb[w16 * 128 + t];
    atomicAdd(&gsum1[t], s);
  } else if (t < 128) {
    int e = t - 64;
    float s = 0.f;
    #pragma unroll
    for (int w16 = 0; w16 < 16; w16++) s += redb[w16 * 128 + 64 + e];
    atomicAdd(&gss1[e], s);
  }
}

// ---- K5: BN2 stats over z = relu(bn1(agg))*W_emb; BN1 coefs inline --------
__global__ __launch_bounds__(256) void k_zstats4(
    const unsigned* __restrict__ aggb, const float* __restrict__ W_emb,
    const float* __restrict__ gsum1, const float* __restrict__ gss1,
    const float* __restrict__ g_bn1, const float* __restrict__ b_bn1,
    float* __restrict__ gsum2, float* __restrict__ gss2) {
  __shared__ float red[4][8][32];
  const float invn = 1.f / (float)NTOT;
  int t = threadIdx.x;
  int gid = blockIdx.x * 256 + t;
  int p = t & 31;                  // channel pair id, fixed across iters
  int c0 = 2 * p;
  float m0 = gsum1[c0] * invn, vv0 = gss1[c0] * invn - m0 * m0;
  float a10 = g_bn1[c0] * rsqrtf(vv0 + EPSBN), c10 = b_bn1[c0] - m0 * a10;
  float m1 = gsum1[c0 + 1] * invn, vv1 = gss1[c0 + 1] * invn - m1 * m1;
  float a11 = g_bn1[c0 + 1] * rsqrtf(vv1 + EPSBN), c11 = b_bn1[c0 + 1] - m1 * a11;
  const float2* we2  = (const float2*)W_emb;
  float ps0 = 0.f, ps1 = 0.f, q0 = 0.f, q1 = 0.f;
  int stride = gridDim.x * 256;
  for (int idx = gid; idx < NTOT * 32; idx += stride) {
    unsigned u = aggb[idx];
    float vx = bf2f(u & 0xffffu), vy = bf2f(u >> 16);
    int node = (idx >> 5) & (NNODE - 1);
    float2 w = we2[node * 32 + p];
    float z0 = vx * a10 + c10; z0 = z0 > 0.f ? z0 : 0.f; z0 *= w.x;
    float z1 = vy * a11 + c11; z1 = z1 > 0.f ? z1 : 0.f; z1 *= w.y;
    ps0 += z0; q0 += z0 * z0; ps1 += z1; q1 += z1 * z1;
  }
  int g = t >> 5;
  red[0][g][p] = ps0; red[1][g][p] = ps1; red[2][g][p] = q0; red[3][g][p] = q1;
  __syncthreads();
  if (t < 128) {
    int v = t >> 5, p2 = t & 31;
    float s = 0.f;
    #pragma unroll
    for (int k = 0; k < 8; k++) s += red[v][k][p2];
    float* dst = (v & 2) ? gss2 : gsum2;
    atomicAdd(&dst[2 * p2 + (v & 1)], s);
  }
}

// ---- K6: MFMA Gram G = h^T h + column sums + h materialization; BN coefs
//      inline from global stats ---------------------------------------------
__global__ __launch_bounds__(256) void k_gram3(
    const unsigned* __restrict__ aggb, const float* __restrict__ W_emb,
    const float* __restrict__ gsum1, const float* __restrict__ gss1,
    const float* __restrict__ g_bn1, const float* __restrict__ b_bn1,
    const float* __restrict__ gsum2, const float* __restrict__ gss2,
    const float* __restrict__ g_bn2, const float* __restrict__ b_bn2,
    float* __restrict__ Gpart, float* __restrict__ hpart,
    unsigned* __restrict__ hb) {
  __shared__ float smem[4 * 4480];   // per-wave region: ht (phase1) / Gbuf (phase2)
  __shared__ float hred[4][64];
  const float invn = 1.f / (float)NTOT;
  const int t = threadIdx.x, wv = t >> 6, ln = t & 63;
  const int lm = ln & 15, lq = ln >> 4;
  const int r4 = ln & 7, ch8 = ln >> 3;
  const int c0 = ch8 * 8;
  float a1v[8], c1v[8], a2v[8], c2v[8];
  #pragma unroll
  for (int j = 0; j < 8; j++) {
    int ch = c0 + j;
    float m = gsum1[ch] * invn, vv = gss1[ch] * invn - m * m;
    a1v[j] = g_bn1[ch] * rsqrtf(vv + EPSBN); c1v[j] = b_bn1[ch] - m * a1v[j];
    float m2 = gsum2[ch] * invn, v2 = gss2[ch] * invn - m2 * m2;
    a2v[j] = g_bn2[ch] * rsqrtf(v2 + EPSBN); c2v[j] = b_bn2[ch] - m2 * a2v[j];
  }
  unsigned* ht = (unsigned*)(smem + wv * 4480);
  bf16x8 ones;
  #pragma unroll
  for (int j = 0; j < 8; j++) ones[j] = (short)0x3F80;
  f32x4 acc[4][4];
  f32x4 accS[4];
  #pragma unroll
  for (int i = 0; i < 4; i++) {
    accS[i] = (f32x4){0.f, 0.f, 0.f, 0.f};
    #pragma unroll
    for (int j = 0; j < 4; j++) acc[i][j] = (f32x4){0.f, 0.f, 0.f, 0.f};
  }
  const uint4* ab4 = (const uint4*)aggb;
  uint4* hb4 = (uint4*)hb;
  const float4* we4 = (const float4*)W_emb;
  const int blockrow = blockIdx.x * 256;
  #pragma unroll
  for (int ck = 0; ck < 2; ck++) {
    int k0 = blockrow + wv * 64 + ck * 32;
    #pragma unroll
    for (int rr2 = 0; rr2 < 2; rr2++) {
      float h2[2][8];
      #pragma unroll
      for (int rh = 0; rh < 2; rh++) {
        int lr = r4 * 4 + rr2 * 2 + rh;
        int row = k0 + lr;
        int node = row & (NNODE - 1);
        uint4 u = ab4[(size_t)row * 8 + ch8];
        float4 w0 = we4[node * 16 + ch8 * 2];
        float4 w1 = we4[node * 16 + ch8 * 2 + 1];
        float gv[8] = {bf2f(u.x & 0xffffu), bf2f(u.x >> 16),
                       bf2f(u.y & 0xffffu), bf2f(u.y >> 16),
                       bf2f(u.z & 0xffffu), bf2f(u.z >> 16),
                       bf2f(u.w & 0xffffu), bf2f(u.w >> 16)};
        float wv8[8] = {w0.x, w0.y, w0.z, w0.w, w1.x, w1.y, w1.z, w1.w};
        #pragma unroll
        for (int j = 0; j < 8; j++) {
          float z = gv[j] * a1v[j] + c1v[j];
          z = z > 0.f ? z : 0.f;
          z *= wv8[j];
          float hh = z * a2v[j] + c2v[j];
          hh = hh > 0.f ? hh : 0.f;
          h2[rh][j] = hh;
        }
        hb4[(size_t)row * 8 + ch8] =
            make_uint4(pkbf(h2[rh][0], h2[rh][1]), pkbf(h2[rh][2], h2[rh][3]),
                       pkbf(h2[rh][4], h2[rh][5]), pkbf(h2[rh][6], h2[rh][7]));
      }
      #pragma unroll
      for (int cc = 0; cc < 8; cc++) {
        int ch = c0 + cc;
        int base = ch * 20 + ((ch >> 3) & 3) * 4;   // swizzled base, 16B-aligned
        ht[base + r4 * 2 + rr2] = pkbf(h2[0][cc], h2[1][cc]);
      }
    }
    bf16x8 frag[4];
    #pragma unroll
    for (int i = 0; i < 4; i++) {
      int ch = i * 16 + lm;
      int base = ch * 20 + ((ch >> 3) & 3) * 4;
      frag[i] = *(const bf16x8*)(ht + base + lq * 4);
    }
    #pragma unroll
    for (int i = 0; i < 4; i++) {
      #pragma unroll
      for (int j = 0; j < 4; j++)
        acc[i][j] = __builtin_amdgcn_mfma_f32_16x16x32_bf16(frag[i], frag[j], acc[i][j], 0, 0, 0);
      accS[i] = __builtin_amdgcn_mfma_f32_16x16x32_bf16(frag[i], ones, accS[i], 0, 0, 0);
    }
  }
  __syncthreads();   // all waves done with ht before Gbuf overwrite
  float* Gb = smem + wv * 4480;    // col-major, pitch 68 (G symmetric)
  #pragma unroll
  for (int i = 0; i < 4; i++) {
    #pragma unroll
    for (int j = 0; j < 4; j++) {
      float4 vv = {acc[i][j][0], acc[i][j][1], acc[i][j][2], acc[i][j][3]};
      *(float4*)(Gb + (j * 16 + lm) * 68 + i * 16 + lq * 4) = vv;
    }
    if (lm == 0) {
      float4 sv = {accS[i][0], accS[i][1], accS[i][2], accS[i][3]};
      *(float4*)&hred[wv][i * 16 + lq * 4] = sv;
    }
  }
  __syncthreads();
  for (int k = t; k < 4096; k += 256) {
    int col = k >> 6, row = k & 63;
    int o = col * 68 + row;
    Gpart[(size_t)blockIdx.x * 4096 + k] =
        smem[o] + smem[4480 + o] + smem[2 * 4480 + o] + smem[3 * 4480 + o];
  }
  if (t < 64)
    hpart[(size_t)blockIdx.x * 64 + t] =
        hred[0][t] + hred[1][t] + hred[2][t] + hred[3][t];
}

// ---- K6b: reduce Gpart/hpart — wide (16-deep sums, 32-way atomic finish) ---
__global__ __launch_bounds__(256) void k_gred(const float* __restrict__ Gpart,
                                              const float* __restrict__ hpart,
                                              float* __restrict__ G,
                                              float* __restrict__ hsum) {
  int wi = blockIdx.x * 256 + threadIdx.x;   // grid 514*256
  if (wi < 131072) {
    int e = wi & 4095, seg = wi >> 12;       // 32 segments of 16 blocks
    float s = 0.f;
    #pragma unroll
    for (int k = 0; k < 16; k++) s += Gpart[(size_t)(seg * 16 + k) * 4096 + e];
    atomicAdd(&G[e], s);
  } else if (wi < 131072 + 512) {
    int wi2 = wi - 131072;
    int e = wi2 & 63, seg = wi2 >> 6;        // 8 segments of 64 blocks
    float s = 0.f;
    #pragma unroll 8
    for (int k = 0; k < 64; k++) s += hpart[(size_t)(seg * 64 + k) * 64 + e];
    atomicAdd(&hsum[e], s);
  }
}

// ---- K6c: BN3 coefs from Gram: per channel c quadform W1c^T G W1c ----------
__global__ __launch_bounds__(64) void k_fin3q(
    const float* __restrict__ G, const float* __restrict__ hsum,
    const float* __restrict__ W1, const float* __restrict__ b1,
    const float* __restrict__ g3, const float* __restrict__ b3,
    float* __restrict__ a3, float* __restrict__ c3) {
  __shared__ float sw[64];
  int c = blockIdx.x, i = threadIdx.x;
  float w1i = W1[c * 64 + i];
  sw[i] = w1i;
  __syncthreads();
  float gw = 0.f;
  #pragma unroll
  for (int j = 0; j < 64; j++) gw += G[j * 64 + i] * sw[j];   // G symmetric
  float t1 = w1i * gw;       // -> quadform
  float t2 = w1i * hsum[i];  // -> sum of dots
  for (int o = 32; o > 0; o >>= 1) { t1 += __shfl_xor(t1, o); t2 += __shfl_xor(t2, o); }
  if (i == 0) {
    float b1c = b1[c];
    const float fn = (float)NTOT, invn = 1.f / fn;
    float sum3 = t2 + fn * b1c;
    float ss3  = t1 + 2.f * b1c * t2 + fn * b1c * b1c;
    float m = sum3 * invn;
    float v = ss3 * invn - m * m;
    float aa = g3[c] * rsqrtf(v + EPSBN);
    a3[c] = aa;
    c3[c] = b3[c] - m * aa;
  }
}

// ---- K7: output GEMM — barrier-free, LDS-free; atomicAdd combine -----------
__global__ __launch_bounds__(512) void k_gout3(
    const unsigned* __restrict__ hb, const float* __restrict__ W1,
    const float* __restrict__ b1, const float* __restrict__ a3,
    const float* __restrict__ c3, const float* __restrict__ W2,
    const float* __restrict__ b2, float* __restrict__ out) {
  const int t = threadIdx.x, wv = t >> 6, ln = t & 63;
  const int lm = ln & 15, lq = ln >> 4, kb = lq * 8;
  bf16x8 bfrag[4][2];
  float b1c[4], a3c[4], c3c[4], w2c[4];
  #pragma unroll
  for (int nt = 0; nt < 4; nt++) {
    int col = wv * 64 + nt * 16 + lm;
    b1c[nt] = b1[col]; a3c[nt] = a3[col]; c3c[nt] = c3[col]; w2c[nt] = W2[col];
    #pragma unroll
    for (int s = 0; s < 2; s++) {
      const float* wp = W1 + col * EMBD + s * 32 + kb;
      float4 w0 = *(const float4*)wp;
      float4 w1 = *(const float4*)(wp + 4);
      U8 f;
      f.u = make_uint4(pkbf(w0.x, w0.y), pkbf(w0.z, w0.w),
                       pkbf(w1.x, w1.y), pkbf(w1.z, w1.w));
      bfrag[nt][s] = f.b;
    }
  }
  float b2v = b2[0];
  const uint4* h4 = (const uint4*)hb;
  for (int tile = blockIdx.x; tile < NTOT / 16; tile += gridDim.x) {
    int rowbase = tile * 16;
    U8 ua, ub;
    ua.u = h4[(size_t)(rowbase + lm) * 8 + lq];       // k-half 0
    ub.u = h4[(size_t)(rowbase + lm) * 8 + 4 + lq];   // k-half 1
    f32x4 acc[4];
    #pragma unroll
    for (int nt = 0; nt < 4; nt++) acc[nt] = (f32x4){0.f, 0.f, 0.f, 0.f};
    #pragma unroll
    for (int nt = 0; nt < 4; nt++)
      acc[nt] = __builtin_amdgcn_mfma_f32_16x16x32_bf16(ua.b, bfrag[nt][0], acc[nt], 0, 0, 0);
    #pragma unroll
    for (int nt = 0; nt < 4; nt++)
      acc[nt] = __builtin_amdgcn_mfma_f32_16x16x32_bf16(ub.b, bfrag[nt][1], acc[nt], 0, 0, 0);
    #pragma unroll
    for (int r = 0; r < 4; r++) {
      float p = 0.f;
      #pragma unroll
      for (int nt = 0; nt < 4; nt++) {
        float z2 = acc[nt][r] + b1c[nt];
        float y = z2 * a3c[nt] + c3c[nt];
        y = y > 0.f ? y : 0.f;
        p += y * w2c[nt];
      }
      p += __shfl_xor(p, 1); p += __shfl_xor(p, 2);
      p += __shfl_xor(p, 4); p += __shfl_xor(p, 8);
      if (lm == 0) {
        if (wv == 0) p += b2v;
        atomicAdd(&out[rowbase + lq * 4 + r], p);
      }
    }
  }
}

extern "C" void kernel_launch(void* const* d_in, const int* in_sizes, int n_in,
                              void* d_out, int out_size, void* d_ws, size_t ws_size,
                              hipStream_t stream) {
  const float* data     = (const float*)d_in[0];
  // d_in[1] org_edge_index: unused by forward
  const float* W_emb    = (const float*)d_in[2];
  const float* W_lin    = (const float*)d_in[3];
  const float* att_i    = (const float*)d_in[4];
  const float* att_j    = (const float*)d_in[5];
  const float* att_em_i = (const float*)d_in[6];
  const float* att_em_j = (const float*)d_in[7];
  // d_in[8] b_gnn: cancels exactly inside training-mode BN1
  const float* g_bn1    = (const float*)d_in[9];
  const float* b_bn1    = (const float*)d_in[10];
  const float* g_bn2    = (const float*)d_in[11];
  const float* b_bn2    = (const float*)d_in[12];
  const float* W1       = (const float*)d_in[13];
  const float* b1       = (const float*)d_in[14];
  const float* g_bn3    = (const float*)d_in[15];
  const float* b_bn3    = (const float*)d_in[16];
  const float* W2       = (const float*)d_in[17];
  const float* b2       = (const float*)d_in[18];
  float* out = (float*)d_out;

  char* p = (char*)d_ws;
  auto alloc = [&](size_t bytes) {
    void* r = (void*)p;
    p += (bytes + 255) & ~(size_t)255;
    return r;
  };
  unsigned* aggb  = (unsigned*)alloc((size_t)NTOT * EMBD * 2);   // 16.8 MB bf16
  unsigned* hb    = (unsigned*)alloc((size_t)NTOT * EMBD * 2);   // 16.8 MB bf16
  float*    Gpart = (float*)alloc((size_t)512 * 4096 * 4);       // 8.4 MB
  float*    hpart = (float*)alloc((size_t)512 * 64 * 4);
  float*    nw    = (float*)alloc((size_t)NNODE * EMBD * 4);
  float*    emb_si = (float*)alloc(NNODE * 4);
  float*    emb_sj = (float*)alloc(NNODE * 4);
  int*      topk   = (int*)alloc(NNODE * KTOP * 4);
  float*    stats  = (float*)alloc(4416 * 4);   // gsum1,gss1,gsum2,gss2,G,hsum
  float*    coefs  = (float*)alloc(1280 * 4);   // a3,c3

  float* gsum1 = stats;       float* gss1 = stats + 64;
  float* gsum2 = stats + 128; float* gss2 = stats + 192;
  float* G     = stats + 256; float* hsum = stats + 4352;
  float* a3 = coefs;          float* c3 = coefs + 512;

  hipMemsetAsync(stats, 0, 4416 * 4, stream);
  hipMemsetAsync(out, 0, (size_t)NTOT * 4, stream);

  k_prep<<<NNODE, 64, 0, stream>>>(W_emb, att_em_i, att_em_j, nw, emb_si, emb_sj);
  k_topk<<<NNODE, 256, 0, stream>>>(nw, topk);
  k_fuse4<<<BATCH, 1024, 0, stream>>>(data, W_lin, att_i, att_j, emb_si, emb_sj,
                                      topk, aggb, gsum1, gss1);
  k_zstats4<<<1024, 256, 0, stream>>>(aggb, W_emb, gsum1, gss1, g_bn1, b_bn1,
                                      gsum2, gss2);
  k_gram3<<<512, 256, 0, stream>>>(aggb, W_emb, gsum1, gss1, g_bn1, b_bn1,
                                   gsum2, gss2, g_bn2, b_bn2, Gpart, hpart, hb);
  k_gred<<<514, 256, 0, stream>>>(Gpart, hpart, G, hsum);
  k_fin3q<<<CIN, 64, 0, stream>>>(G, hsum, W1, b1, g_bn3, b_bn3, a3, c3);
  k_gout3<<<512, 512, 0, stream>>>(hb, W1, b1, a3, c3, W2, b2, out);
}

// Round 11
// 253.624 us; speedup vs baseline: 1.0250x; 1.0250x over previous
//
#include <hip/hip_runtime.h>
#include <hip/hip_bf16.h>

constexpr int BATCH = 256, NNODE = 512, WINW = 64, EMBD = 64, KTOP = 16, CIN = 512;
constexpr int NTOT = BATCH * NNODE;          // 131072
constexpr float NEGS = 0.2f;
constexpr float EPSBN = 1e-5f;
constexpr int XLP = 68;                      // LDS pitch for xl (2-way banks)

typedef __attribute__((ext_vector_type(8))) short bf16x8;
typedef __attribute__((ext_vector_type(4))) float f32x4;

union U8 { uint4 u; bf16x8 b; };

__device__ inline float bf2f(unsigned u16) {
  union { unsigned u; float f; } v; v.u = u16 << 16; return v.f;
}
// packed fp32x2 -> bf16x2 (v_cvt_pk_bf16_f32), a in low half
__device__ inline unsigned pkbf(float a, float b) {
  __hip_bfloat162 h = __float22bfloat162_rn(make_float2(a, b));
  return *(unsigned*)&h;
}

// ---- K0: normalize embeddings + per-node attention-embedding dots ----------
__global__ void k_prep(const float* __restrict__ W_emb,
                       const float* __restrict__ att_em_i,
                       const float* __restrict__ att_em_j,
                       float* __restrict__ nw, float* __restrict__ emb_si,
                       float* __restrict__ emb_sj) {
  int i = blockIdx.x, e = threadIdx.x;   // block = 64 threads
  float w  = W_emb[i * EMBD + e];
  float sq = w * w;
  float si = w * att_em_i[e];
  float sj = w * att_em_j[e];
  for (int o = 32; o > 0; o >>= 1) {
    sq += __shfl_xor(sq, o);
    si += __shfl_xor(si, o);
    sj += __shfl_xor(sj, o);
  }
  nw[i * EMBD + e] = w * rsqrtf(sq);
  if (e == 0) { emb_si[i] = si; emb_sj[i] = sj; }
}

// ---- K1: cosine top-16 per node — shuffle argmax ---------------------------
__global__ __launch_bounds__(256) void k_topk(const float* __restrict__ nw,
                                              int* __restrict__ topk) {
  __shared__ float nwi[EMBD];
  __shared__ float wbv[4];
  __shared__ int   wbi[4];
  __shared__ int   winner;
  int i = blockIdx.x, t = threadIdx.x, wv = t >> 6, ln = t & 63;
  if (t < EMBD) nwi[t] = nw[i * EMBD + t];
  __syncthreads();
  float v0 = 0.f, v1 = 0.f;
  #pragma unroll
  for (int k = 0; k < EMBD; k++) {
    v0 += nw[t * EMBD + k] * nwi[k];
    v1 += nw[(t + 256) * EMBD + k] * nwi[k];
  }
  for (int sel = 0; sel < KTOP; sel++) {
    float bv; int bi;
    if (v1 > v0) { bv = v1; bi = t + 256; } else { bv = v0; bi = t; }  // tie -> lower idx
    #pragma unroll
    for (int o = 1; o < 64; o <<= 1) {
      float ov = __shfl_xor(bv, o);
      int   oi = __shfl_xor(bi, o);
      if (ov > bv || (ov == bv && oi < bi)) { bv = ov; bi = oi; }
    }
    if (ln == 0) { wbv[wv] = bv; wbi[wv] = bi; }
    __syncthreads();
    if (t == 0) {
      float B = wbv[0]; int I = wbi[0];
      #pragma unroll
      for (int w = 1; w < 4; w++)
        if (wbv[w] > B || (wbv[w] == B && wbi[w] < I)) { B = wbv[w]; I = wbi[w]; }
      topk[i * KTOP + sel] = I;
      winner = I;
    }
    __syncthreads();
    int wi = winner;
    if (wi == t) v0 = -3.f;
    else if (wi == t + 256) v1 = -3.f;
  }
}

// ============================================================================
// K_FUSE5: one block per batch (grid=256, 1024 thr = 16 waves).
// Phase A: xl = x @ W_lin^T via bf16 MFMA -> LDS fp32 (pitch 68).
// Phase B: lane-parallel softmax (1 exp/lane, shuffle reductions); pre-scaled
//   weights staged in per-wave LDS row, read back via 4 broadcast b128 reads
//   (no bpermute). agg -> global bf16 + BN1 stats.
// ============================================================================
__global__ __launch_bounds__(1024) void k_fuse5(
    const float* __restrict__ data, const float* __restrict__ W_lin,
    const float* __restrict__ att_i, const float* __restrict__ att_j,
    const float* __restrict__ emb_si, const float* __restrict__ emb_sj,
    const int* __restrict__ topk,
    unsigned* __restrict__ aggb, float* __restrict__ gsum1,
    float* __restrict__ gss1) {
  __shared__ float xl[NNODE * XLP];       // 136 KB
  __shared__ float ssi[NNODE];            // 2 KB
  __shared__ float ssj[NNODE];            // 2 KB
  __shared__ float ews[16][64];           // 4 KB: per-wave weight staging
  __shared__ float redb[16 * 128];        // 8 KB
  const int b = blockIdx.x;
  const int t = threadIdx.x, w = t >> 6, ln = t & 63;
  const int lm = ln & 15, lq = ln >> 4, kb = lq * 8;

  bf16x8 bfrag[4][2];
  float ai4[4], aj4[4];
  #pragma unroll
  for (int ti = 0; ti < 4; ti++) {
    int ch = ti * 16 + lm;
    ai4[ti] = att_i[ch]; aj4[ti] = att_j[ch];
    #pragma unroll
    for (int s = 0; s < 2; s++) {
      const float* wp = W_lin + ch * WINW + s * 32 + kb;
      float4 w0 = *(const float4*)wp;
      float4 w1 = *(const float4*)(wp + 4);
      U8 f;
      f.u = make_uint4(pkbf(w0.x, w0.y), pkbf(w0.z, w0.w),
                       pkbf(w1.x, w1.y), pkbf(w1.z, w1.w));
      bfrag[ti][s] = f.b;
    }
  }
  // ---- phase A ----
  #pragma unroll
  for (int tt = 0; tt < 2; tt++) {
    int tile = w * 2 + tt;
    const float* dr = data + ((size_t)b * NNODE + tile * 16 + lm) * WINW + kb;
    f32x4 acc[4];
    #pragma unroll
    for (int ti = 0; ti < 4; ti++) acc[ti] = (f32x4){0.f, 0.f, 0.f, 0.f};
    #pragma unroll
    for (int s = 0; s < 2; s++) {
      float4 d0 = *(const float4*)(dr + s * 32);
      float4 d1 = *(const float4*)(dr + s * 32 + 4);
      U8 af;
      af.u = make_uint4(pkbf(d0.x, d0.y), pkbf(d0.z, d0.w),
                        pkbf(d1.x, d1.y), pkbf(d1.z, d1.w));
      #pragma unroll
      for (int ti = 0; ti < 4; ti++)
        acc[ti] = __builtin_amdgcn_mfma_f32_16x16x32_bf16(af.b, bfrag[ti][s], acc[ti], 0, 0, 0);
    }
    #pragma unroll
    for (int r = 0; r < 4; r++) {
      int nd = tile * 16 + lq * 4 + r;
      float si = 0.f, sj = 0.f;
      #pragma unroll
      for (int ti = 0; ti < 4; ti++) {
        float v = acc[ti][r];
        xl[nd * XLP + ti * 16 + lm] = v;
        si += v * ai4[ti];
        sj += v * aj4[ti];
      }
      si += __shfl_xor(si, 1); si += __shfl_xor(si, 2);
      si += __shfl_xor(si, 4); si += __shfl_xor(si, 8);
      sj += __shfl_xor(sj, 1); sj += __shfl_xor(sj, 2);
      sj += __shfl_xor(sj, 4); sj += __shfl_xor(sj, 8);
      if (lm == 0) { ssi[nd] = si + emb_si[nd]; ssj[nd] = sj + emb_sj[nd]; }
    }
  }
  __syncthreads();
  // ---- phase B: 4 dst nodes per wave-pass; lane = (nd4, l4) ----
  const int nd4 = ln >> 4, l4 = ln & 15;
  float psx = 0.f, psy = 0.f, psz = 0.f, psw = 0.f;
  float qsx = 0.f, qsy = 0.f, qsz = 0.f, qsw = 0.f;
  for (int it = 0; it < 8; it++) {
    int node = w * 32 + it * 4 + nd4;
    const int4* tp = (const int4*)(topk + node * KTOP);
    int4 i0 = tp[0], i1 = tp[1], i2 = tp[2], i3 = tp[3];
    int idx[16] = {i0.x, i0.y, i0.z, i0.w, i1.x, i1.y, i1.z, i1.w,
                   i2.x, i2.y, i2.z, i2.w, i3.x, i3.y, i3.z, i3.w};
    float a = ssi[node] + ssj[idx[l4]];
    a = a > 0.f ? a : NEGS * a;           // leaky_relu
    float mx = a;
    mx = fmaxf(mx, __shfl_xor(mx, 1));
    mx = fmaxf(mx, __shfl_xor(mx, 2));
    mx = fmaxf(mx, __shfl_xor(mx, 4));
    mx = fmaxf(mx, __shfl_xor(mx, 8));
    float e = __expf(a - mx);
    float den = e;
    den += __shfl_xor(den, 1); den += __shfl_xor(den, 2);
    den += __shfl_xor(den, 4); den += __shfl_xor(den, 8);
    ews[w][ln] = e / den;                 // pre-scaled weight (wave-synchronous)
    // read back this group's 16 weights: 4 broadcast b128 reads
    float4 w0 = *(const float4*)&ews[w][nd4 * 16 + 0];
    float4 w1 = *(const float4*)&ews[w][nd4 * 16 + 4];
    float4 w2 = *(const float4*)&ews[w][nd4 * 16 + 8];
    float4 w3 = *(const float4*)&ews[w][nd4 * 16 + 12];
    float wks[16] = {w0.x, w0.y, w0.z, w0.w, w1.x, w1.y, w1.z, w1.w,
                     w2.x, w2.y, w2.z, w2.w, w3.x, w3.y, w3.z, w3.w};
    float ax = 0.f, ay = 0.f, az = 0.f, aw = 0.f;
    #pragma unroll
    for (int k = 0; k < KTOP; k++) {
      float4 v = *(const float4*)&xl[idx[k] * XLP + l4 * 4];
      ax += wks[k] * v.x; ay += wks[k] * v.y;
      az += wks[k] * v.z; aw += wks[k] * v.w;
    }
    uint2 st = make_uint2(pkbf(ax, ay), pkbf(az, aw));
    *(uint2*)(aggb + (((size_t)b * NNODE + node) << 5) + l4 * 2) = st;
    psx += ax; psy += ay; psz += az; psw += aw;
    qsx += ax * ax; qsy += ay * ay; qsz += az * az; qsw += aw * aw;
  }
  #pragma unroll
  for (int o = 16; o <= 32; o <<= 1) {
    psx += __shfl_xor(psx, o); psy += __shfl_xor(psy, o);
    psz += __shfl_xor(psz, o); psw += __shfl_xor(psw, o);
    qsx += __shfl_xor(qsx, o); qsy += __shfl_xor(qsy, o);
    qsz += __shfl_xor(qsz, o); qsw += __shfl_xor(qsw, o);
  }
  if (ln < 16) {
    float4 a = {psx, psy, psz, psw};
    float4 q = {qsx, qsy, qsz, qsw};
    *(float4*)&redb[w * 128 + ln * 4] = a;
    *(float4*)&redb[w * 128 + 64 + ln * 4] = q;
  }
  __syncthreads();
  if (t < 64) {
    float s = 0.f;
    #pragma unroll
    for (int w16 = 0; w16 < 16; w16++) s += redb[w16 * 128 + t];
    atomicAdd(&gsum1[t], s);
  } else if (t < 128) {
    int e = t - 64;
    float s = 0.f;
    #pragma unroll
    for (int w16 = 0; w16 < 16; w16++) s += redb[w16 * 128 + 64 + e];
    atomicAdd(&gss1[e], s);
  }
}

// ---- K5: BN2 stats over z = relu(bn1(agg))*W_emb; BN1 coefs inline --------
__global__ __launch_bounds__(256) void k_zstats4(
    const unsigned* __restrict__ aggb, const float* __restrict__ W_emb,
    const float* __restrict__ gsum1, const float* __restrict__ gss1,
    const float* __restrict__ g_bn1, const float* __restrict__ b_bn1,
    float* __restrict__ gsum2, float* __restrict__ gss2) {
  __shared__ float red[4][8][32];
  const float invn = 1.f / (float)NTOT;
  int t = threadIdx.x;
  int gid = blockIdx.x * 256 + t;
  int p = t & 31;                  // channel pair id, fixed across iters
  int c0 = 2 * p;
  float m0 = gsum1[c0] * invn, vv0 = gss1[c0] * invn - m0 * m0;
  float a10 = g_bn1[c0] * rsqrtf(vv0 + EPSBN), c10 = b_bn1[c0] - m0 * a10;
  float m1 = gsum1[c0 + 1] * invn, vv1 = gss1[c0 + 1] * invn - m1 * m1;
  float a11 = g_bn1[c0 + 1] * rsqrtf(vv1 + EPSBN), c11 = b_bn1[c0 + 1] - m1 * a11;
  const float2* we2  = (const float2*)W_emb;
  float ps0 = 0.f, ps1 = 0.f, q0 = 0.f, q1 = 0.f;
  int stride = gridDim.x * 256;
  for (int idx = gid; idx < NTOT * 32; idx += stride) {
    unsigned u = aggb[idx];
    float vx = bf2f(u & 0xffffu), vy = bf2f(u >> 16);
    int node = (idx >> 5) & (NNODE - 1);
    float2 w = we2[node * 32 + p];
    float z0 = vx * a10 + c10; z0 = z0 > 0.f ? z0 : 0.f; z0 *= w.x;
    float z1 = vy * a11 + c11; z1 = z1 > 0.f ? z1 : 0.f; z1 *= w.y;
    ps0 += z0; q0 += z0 * z0; ps1 += z1; q1 += z1 * z1;
  }
  int g = t >> 5;
  red[0][g][p] = ps0; red[1][g][p] = ps1; red[2][g][p] = q0; red[3][g][p] = q1;
  __syncthreads();
  if (t < 128) {
    int v = t >> 5, p2 = t & 31;
    float s = 0.f;
    #pragma unroll
    for (int k = 0; k < 8; k++) s += red[v][k][p2];
    float* dst = (v & 2) ? gss2 : gsum2;
    atomicAdd(&dst[2 * p2 + (v & 1)], s);
  }
}

// ---- K6: MFMA Gram G = h^T h + column sums + h materialization; BN coefs
//      inline from global stats ---------------------------------------------
__global__ __launch_bounds__(256) void k_gram3(
    const unsigned* __restrict__ aggb, const float* __restrict__ W_emb,
    const float* __restrict__ gsum1, const float* __restrict__ gss1,
    const float* __restrict__ g_bn1, const float* __restrict__ b_bn1,
    const float* __restrict__ gsum2, const float* __restrict__ gss2,
    const float* __restrict__ g_bn2, const float* __restrict__ b_bn2,
    float* __restrict__ Gpart, float* __restrict__ hpart,
    unsigned* __restrict__ hb) {
  __shared__ float smem[4 * 4480];   // per-wave region: ht (phase1) / Gbuf (phase2)
  __shared__ float hred[4][64];
  const float invn = 1.f / (float)NTOT;
  const int t = threadIdx.x, wv = t >> 6, ln = t & 63;
  const int lm = ln & 15, lq = ln >> 4;
  const int r4 = ln & 7, ch8 = ln >> 3;
  const int c0 = ch8 * 8;
  float a1v[8], c1v[8], a2v[8], c2v[8];
  #pragma unroll
  for (int j = 0; j < 8; j++) {
    int ch = c0 + j;
    float m = gsum1[ch] * invn, vv = gss1[ch] * invn - m * m;
    a1v[j] = g_bn1[ch] * rsqrtf(vv + EPSBN); c1v[j] = b_bn1[ch] - m * a1v[j];
    float m2 = gsum2[ch] * invn, v2 = gss2[ch] * invn - m2 * m2;
    a2v[j] = g_bn2[ch] * rsqrtf(v2 + EPSBN); c2v[j] = b_bn2[ch] - m2 * a2v[j];
  }
  unsigned* ht = (unsigned*)(smem + wv * 4480);
  bf16x8 ones;
  #pragma unroll
  for (int j = 0; j < 8; j++) ones[j] = (short)0x3F80;
  f32x4 acc[4][4];
  f32x4 accS[4];
  #pragma unroll
  for (int i = 0; i < 4; i++) {
    accS[i] = (f32x4){0.f, 0.f, 0.f, 0.f};
    #pragma unroll
    for (int j = 0; j < 4; j++) acc[i][j] = (f32x4){0.f, 0.f, 0.f, 0.f};
  }
  const uint4* ab4 = (const uint4*)aggb;
  uint4* hb4 = (uint4*)hb;
  const float4* we4 = (const float4*)W_emb;
  const int blockrow = blockIdx.x * 256;
  #pragma unroll
  for (int ck = 0; ck < 2; ck++) {
    int k0 = blockrow + wv * 64 + ck * 32;
    #pragma unroll
    for (int rr2 = 0; rr2 < 2; rr2++) {
      float h2[2][8];
      #pragma unroll
      for (int rh = 0; rh < 2; rh++) {
        int lr = r4 * 4 + rr2 * 2 + rh;
        int row = k0 + lr;
        int node = row & (NNODE - 1);
        uint4 u = ab4[(size_t)row * 8 + ch8];
        float4 w0 = we4[node * 16 + ch8 * 2];
        float4 w1 = we4[node * 16 + ch8 * 2 + 1];
        float gv[8] = {bf2f(u.x & 0xffffu), bf2f(u.x >> 16),
                       bf2f(u.y & 0xffffu), bf2f(u.y >> 16),
                       bf2f(u.z & 0xffffu), bf2f(u.z >> 16),
                       bf2f(u.w & 0xffffu), bf2f(u.w >> 16)};
        float wv8[8] = {w0.x, w0.y, w0.z, w0.w, w1.x, w1.y, w1.z, w1.w};
        #pragma unroll
        for (int j = 0; j < 8; j++) {
          float z = gv[j] * a1v[j] + c1v[j];
          z = z > 0.f ? z : 0.f;
          z *= wv8[j];
          float hh = z * a2v[j] + c2v[j];
          hh = hh > 0.f ? hh : 0.f;
          h2[rh][j] = hh;
        }
        hb4[(size_t)row * 8 + ch8] =
            make_uint4(pkbf(h2[rh][0], h2[rh][1]), pkbf(h2[rh][2], h2[rh][3]),
                       pkbf(h2[rh][4], h2[rh][5]), pkbf(h2[rh][6], h2[rh][7]));
      }
      #pragma unroll
      for (int cc = 0; cc < 8; cc++) {
        int ch = c0 + cc;
        int base = ch * 20 + ((ch >> 3) & 3) * 4;   // swizzled base, 16B-aligned
        ht[base + r4 * 2 + rr2] = pkbf(h2[0][cc], h2[1][cc]);
      }
    }
    bf16x8 frag[4];
    #pragma unroll
    for (int i = 0; i < 4; i++) {
      int ch = i * 16 + lm;
      int base = ch * 20 + ((ch >> 3) & 3) * 4;
      frag[i] = *(const bf16x8*)(ht + base + lq * 4);
    }
    #pragma unroll
    for (int i = 0; i < 4; i++) {
      #pragma unroll
      for (int j = 0; j < 4; j++)
        acc[i][j] = __builtin_amdgcn_mfma_f32_16x16x32_bf16(frag[i], frag[j], acc[i][j], 0, 0, 0);
      accS[i] = __builtin_amdgcn_mfma_f32_16x16x32_bf16(frag[i], ones, accS[i], 0, 0, 0);
    }
  }
  __syncthreads();   // all waves done with ht before Gbuf overwrite
  float* Gb = smem + wv * 4480;    // col-major, pitch 68 (G symmetric)
  #pragma unroll
  for (int i = 0; i < 4; i++) {
    #pragma unroll
    for (int j = 0; j < 4; j++) {
      float4 vv = {acc[i][j][0], acc[i][j][1], acc[i][j][2], acc[i][j][3]};
      *(float4*)(Gb + (j * 16 + lm) * 68 + i * 16 + lq * 4) = vv;
    }
    if (lm == 0) {
      float4 sv = {accS[i][0], accS[i][1], accS[i][2], accS[i][3]};
      *(float4*)&hred[wv][i * 16 + lq * 4] = sv;
    }
  }
  __syncthreads();
  for (int k = t; k < 4096; k += 256) {
    int col = k >> 6, row = k & 63;
    int o = col * 68 + row;
    Gpart[(size_t)blockIdx.x * 4096 + k] =
        smem[o] + smem[4480 + o] + smem[2 * 4480 + o] + smem[3 * 4480 + o];
  }
  if (t < 64)
    hpart[(size_t)blockIdx.x * 64 + t] =
        hred[0][t] + hred[1][t] + hred[2][t] + hred[3][t];
}

// ---- K6b: reduce Gpart/hpart — wide (16-deep sums, 32-way atomic finish) ---
__global__ __launch_bounds__(256) void k_gred(const float* __restrict__ Gpart,
                                              const float* __restrict__ hpart,
                                              float* __restrict__ G,
                                              float* __restrict__ hsum) {
  int wi = blockIdx.x * 256 + threadIdx.x;   // grid 514*256
  if (wi < 131072) {
    int e = wi & 4095, seg = wi >> 12;       // 32 segments of 16 blocks
    float s = 0.f;
    #pragma unroll
    for (int k = 0; k < 16; k++) s += Gpart[(size_t)(seg * 16 + k) * 4096 + e];
    atomicAdd(&G[e], s);
  } else if (wi < 131072 + 512) {
    int wi2 = wi - 131072;
    int e = wi2 & 63, seg = wi2 >> 6;        // 8 segments of 64 blocks
    float s = 0.f;
    #pragma unroll 8
    for (int k = 0; k < 64; k++) s += hpart[(size_t)(seg * 64 + k) * 64 + e];
    atomicAdd(&hsum[e], s);
  }
}

// ---- K6c: BN3 coefs from Gram: per channel c quadform W1c^T G W1c ----------
__global__ __launch_bounds__(64) void k_fin3q(
    const float* __restrict__ G, const float* __restrict__ hsum,
    const float* __restrict__ W1, const float* __restrict__ b1,
    const float* __restrict__ g3, const float* __restrict__ b3,
    float* __restrict__ a3, float* __restrict__ c3) {
  __shared__ float sw[64];
  int c = blockIdx.x, i = threadIdx.x;
  float w1i = W1[c * 64 + i];
  sw[i] = w1i;
  __syncthreads();
  float gw = 0.f;
  #pragma unroll
  for (int j = 0; j < 64; j++) gw += G[j * 64 + i] * sw[j];   // G symmetric
  float t1 = w1i * gw;       // -> quadform
  float t2 = w1i * hsum[i];  // -> sum of dots
  for (int o = 32; o > 0; o >>= 1) { t1 += __shfl_xor(t1, o); t2 += __shfl_xor(t2, o); }
  if (i == 0) {
    float b1c = b1[c];
    const float fn = (float)NTOT, invn = 1.f / fn;
    float sum3 = t2 + fn * b1c;
    float ss3  = t1 + 2.f * b1c * t2 + fn * b1c * b1c;
    float m = sum3 * invn;
    float v = ss3 * invn - m * m;
    float aa = g3[c] * rsqrtf(v + EPSBN);
    a3[c] = aa;
    c3[c] = b3[c] - m * aa;
  }
}

// ---- K7: output GEMM — barrier-free, LDS-free; atomicAdd combine -----------
__global__ __launch_bounds__(512) void k_gout3(
    const unsigned* __restrict__ hb, const float* __restrict__ W1,
    const float* __restrict__ b1, const float* __restrict__ a3,
    const float* __restrict__ c3, const float* __restrict__ W2,
    const float* __restrict__ b2, float* __restrict__ out) {
  const int t = threadIdx.x, wv = t >> 6, ln = t & 63;
  const int lm = ln & 15, lq = ln >> 4, kb = lq * 8;
  bf16x8 bfrag[4][2];
  float b1c[4], a3c[4], c3c[4], w2c[4];
  #pragma unroll
  for (int nt = 0; nt < 4; nt++) {
    int col = wv * 64 + nt * 16 + lm;
    b1c[nt] = b1[col]; a3c[nt] = a3[col]; c3c[nt] = c3[col]; w2c[nt] = W2[col];
    #pragma unroll
    for (int s = 0; s < 2; s++) {
      const float* wp = W1 + col * EMBD + s * 32 + kb;
      float4 w0 = *(const float4*)wp;
      float4 w1 = *(const float4*)(wp + 4);
      U8 f;
      f.u = make_uint4(pkbf(w0.x, w0.y), pkbf(w0.z, w0.w),
                       pkbf(w1.x, w1.y), pkbf(w1.z, w1.w));
      bfrag[nt][s] = f.b;
    }
  }
  float b2v = b2[0];
  const uint4* h4 = (const uint4*)hb;
  for (int tile = blockIdx.x; tile < NTOT / 16; tile += gridDim.x) {
    int rowbase = tile * 16;
    U8 ua, ub;
    ua.u = h4[(size_t)(rowbase + lm) * 8 + lq];       // k-half 0
    ub.u = h4[(size_t)(rowbase + lm) * 8 + 4 + lq];   // k-half 1
    f32x4 acc[4];
    #pragma unroll
    for (int nt = 0; nt < 4; nt++) acc[nt] = (f32x4){0.f, 0.f, 0.f, 0.f};
    #pragma unroll
    for (int nt = 0; nt < 4; nt++)
      acc[nt] = __builtin_amdgcn_mfma_f32_16x16x32_bf16(ua.b, bfrag[nt][0], acc[nt], 0, 0, 0);
    #pragma unroll
    for (int nt = 0; nt < 4; nt++)
      acc[nt] = __builtin_amdgcn_mfma_f32_16x16x32_bf16(ub.b, bfrag[nt][1], acc[nt], 0, 0, 0);
    #pragma unroll
    for (int r = 0; r < 4; r++) {
      float p = 0.f;
      #pragma unroll
      for (int nt = 0; nt < 4; nt++) {
        float z2 = acc[nt][r] + b1c[nt];
        float y = z2 * a3c[nt] + c3c[nt];
        y = y > 0.f ? y : 0.f;
        p += y * w2c[nt];
      }
      p += __shfl_xor(p, 1); p += __shfl_xor(p, 2);
      p += __shfl_xor(p, 4); p += __shfl_xor(p, 8);
      if (lm == 0) {
        if (wv == 0) p += b2v;
        atomicAdd(&out[rowbase + lq * 4 + r], p);
      }
    }
  }
}

extern "C" void kernel_launch(void* const* d_in, const int* in_sizes, int n_in,
                              void* d_out, int out_size, void* d_ws, size_t ws_size,
                              hipStream_t stream) {
  const float* data     = (const float*)d_in[0];
  // d_in[1] org_edge_index: unused by forward
  const float* W_emb    = (const float*)d_in[2];
  const float* W_lin    = (const float*)d_in[3];
  const float* att_i    = (const float*)d_in[4];
  const float* att_j    = (const float*)d_in[5];
  const float* att_em_i = (const float*)d_in[6];
  const float* att_em_j = (const float*)d_in[7];
  // d_in[8] b_gnn: cancels exactly inside training-mode BN1
  const float* g_bn1    = (const float*)d_in[9];
  const float* b_bn1    = (const float*)d_in[10];
  const float* g_bn2    = (const float*)d_in[11];
  const float* b_bn2    = (const float*)d_in[12];
  const float* W1       = (const float*)d_in[13];
  const float* b1       = (const float*)d_in[14];
  const float* g_bn3    = (const float*)d_in[15];
  const float* b_bn3    = (const float*)d_in[16];
  const float* W2       = (const float*)d_in[17];
  const float* b2       = (const float*)d_in[18];
  float* out = (float*)d_out;

  char* p = (char*)d_ws;
  auto alloc = [&](size_t bytes) {
    void* r = (void*)p;
    p += (bytes + 255) & ~(size_t)255;
    return r;
  };
  unsigned* aggb  = (unsigned*)alloc((size_t)NTOT * EMBD * 2);   // 16.8 MB bf16
  unsigned* hb    = (unsigned*)alloc((size_t)NTOT * EMBD * 2);   // 16.8 MB bf16
  float*    Gpart = (float*)alloc((size_t)512 * 4096 * 4);       // 8.4 MB
  float*    hpart = (float*)alloc((size_t)512 * 64 * 4);
  float*    nw    = (float*)alloc((size_t)NNODE * EMBD * 4);
  float*    emb_si = (float*)alloc(NNODE * 4);
  float*    emb_sj = (float*)alloc(NNODE * 4);
  int*      topk   = (int*)alloc(NNODE * KTOP * 4);
  float*    stats  = (float*)alloc(4416 * 4);   // gsum1,gss1,gsum2,gss2,G,hsum
  float*    coefs  = (float*)alloc(1280 * 4);   // a3,c3

  float* gsum1 = stats;       float* gss1 = stats + 64;
  float* gsum2 = stats + 128; float* gss2 = stats + 192;
  float* G     = stats + 256; float* hsum = stats + 4352;
  float* a3 = coefs;          float* c3 = coefs + 512;

  hipMemsetAsync(stats, 0, 4416 * 4, stream);
  hipMemsetAsync(out, 0, (size_t)NTOT * 4, stream);

  k_prep<<<NNODE, 64, 0, stream>>>(W_emb, att_em_i, att_em_j, nw, emb_si, emb_sj);
  k_topk<<<NNODE, 256, 0, stream>>>(nw, topk);
  k_fuse5<<<BATCH, 1024, 0, stream>>>(data, W_lin, att_i, att_j, emb_si, emb_sj,
                                      topk, aggb, gsum1, gss1);
  k_zstats4<<<1024, 256, 0, stream>>>(aggb, W_emb, gsum1, gss1, g_bn1, b_bn1,
                                      gsum2, gss2);
  k_gram3<<<512, 256, 0, stream>>>(aggb, W_emb, gsum1, gss1, g_bn1, b_bn1,
                                   gsum2, gss2, g_bn2, b_bn2, Gpart, hpart, hb);
  k_gred<<<514, 256, 0, stream>>>(Gpart, hpart, G, hsum);
  k_fin3q<<<CIN, 64, 0, stream>>>(G, hsum, W1, b1, g_bn3, b_bn3, a3, c3);
  k_gout3<<<512, 512, 0, stream>>>(hb, W1, b1, a3, c3, W2, b2, out);
}

// Round 12
// 247.645 us; speedup vs baseline: 1.0498x; 1.0241x over previous
//
#include <hip/hip_runtime.h>
#include <hip/hip_bf16.h>

constexpr int BATCH = 256, NNODE = 512, WINW = 64, EMBD = 64, KTOP = 16, CIN = 512;
constexpr int NTOT = BATCH * NNODE;          // 131072
constexpr float NEGS = 0.2f;
constexpr float EPSBN = 1e-5f;
constexpr int XLP = 68;                      // LDS pitch for xl (2-way banks)

typedef __attribute__((ext_vector_type(8))) short bf16x8;
typedef __attribute__((ext_vector_type(4))) float f32x4;

union U8 { uint4 u; bf16x8 b; };

__device__ inline float bf2f(unsigned u16) {
  union { unsigned u; float f; } v; v.u = u16 << 16; return v.f;
}
// packed fp32x2 -> bf16x2 (v_cvt_pk_bf16_f32), a in low half
__device__ inline unsigned pkbf(float a, float b) {
  __hip_bfloat162 h = __float22bfloat162_rn(make_float2(a, b));
  return *(unsigned*)&h;
}

// ---- K0: normalize embeddings + attention-embedding dots + stats zero ------
__global__ void k_prep(const float* __restrict__ W_emb,
                       const float* __restrict__ att_em_i,
                       const float* __restrict__ att_em_j,
                       float* __restrict__ nw, float* __restrict__ emb_si,
                       float* __restrict__ emb_sj, float* __restrict__ stats) {
  int i = blockIdx.x, e = threadIdx.x;   // block = 64 threads
  int gid = i * 64 + e;
  if (gid < 4416) stats[gid] = 0.f;      // folded memset (gsum/gss/G/hsum)
  float w  = W_emb[i * EMBD + e];
  float sq = w * w;
  float si = w * att_em_i[e];
  float sj = w * att_em_j[e];
  for (int o = 32; o > 0; o >>= 1) {
    sq += __shfl_xor(sq, o);
    si += __shfl_xor(si, o);
    sj += __shfl_xor(sj, o);
  }
  nw[i * EMBD + e] = w * rsqrtf(sq);
  if (e == 0) { emb_si[i] = si; emb_sj[i] = sj; }
}

// ---- K1: cosine top-16 per node — wave-0 register selection, 2 barriers ----
__global__ __launch_bounds__(256) void k_topk(const float* __restrict__ nw,
                                              int* __restrict__ topk,
                                              float* __restrict__ out_zero) {
  __shared__ float nwi[EMBD];
  __shared__ float cosv[NNODE];
  int i = blockIdx.x, t = threadIdx.x;
  out_zero[i * 256 + t] = 0.f;           // folded memset of out (512*256 = NTOT)
  if (t < EMBD) nwi[t] = nw[i * EMBD + t];
  __syncthreads();
  float v0 = 0.f, v1 = 0.f;
  #pragma unroll
  for (int k = 0; k < EMBD; k++) {
    v0 += nw[t * EMBD + k] * nwi[k];
    v1 += nw[(t + 256) * EMBD + k] * nwi[k];
  }
  cosv[t] = v0;
  cosv[t + 256] = v1;
  __syncthreads();
  if (t < 64) {                          // wave 0 does all selection in regs
    float vals[8];
    #pragma unroll
    for (int q = 0; q < 8; q++) vals[q] = cosv[t + 64 * q];
    for (int sel = 0; sel < KTOP; sel++) {
      float bv = vals[0]; int bq = 0;
      #pragma unroll
      for (int q = 1; q < 8; q++)
        if (vals[q] > bv) { bv = vals[q]; bq = q; }   // strict > : lower idx wins
      int bi = t + 64 * bq;
      #pragma unroll
      for (int o = 1; o < 64; o <<= 1) {
        float ov = __shfl_xor(bv, o);
        int   oi = __shfl_xor(bi, o);
        if (ov > bv || (ov == bv && oi < bi)) { bv = ov; bi = oi; }
      }
      if (t == 0) topk[i * KTOP + sel] = bi;
      int wq = bi >> 6, wl = bi & 63;
      #pragma unroll
      for (int q = 0; q < 8; q++)
        if (q == wq && t == wl) vals[q] = -3.f;       // remove winner
    }
  }
}

// ============================================================================
// K_FUSE5: one block per batch (grid=256, 1024 thr = 16 waves).
// Phase A: xl = x @ W_lin^T via bf16 MFMA -> LDS fp32 (pitch 68).
// Phase B: lane-parallel softmax (1 exp/lane, shuffle reductions); pre-scaled
//   weights staged in per-wave LDS row, read back via 4 broadcast b128 reads.
//   agg -> global bf16 + BN1 stats.
// ============================================================================
__global__ __launch_bounds__(1024) void k_fuse5(
    const float* __restrict__ data, const float* __restrict__ W_lin,
    const float* __restrict__ att_i, const float* __restrict__ att_j,
    const float* __restrict__ emb_si, const float* __restrict__ emb_sj,
    const int* __restrict__ topk,
    unsigned* __restrict__ aggb, float* __restrict__ gsum1,
    float* __restrict__ gss1) {
  __shared__ float xl[NNODE * XLP];       // 136 KB
  __shared__ float ssi[NNODE];            // 2 KB
  __shared__ float ssj[NNODE];            // 2 KB
  __shared__ float ews[16][64];           // 4 KB: per-wave weight staging
  __shared__ float redb[16 * 128];        // 8 KB
  const int b = blockIdx.x;
  const int t = threadIdx.x, w = t >> 6, ln = t & 63;
  const int lm = ln & 15, lq = ln >> 4, kb = lq * 8;

  bf16x8 bfrag[4][2];
  float ai4[4], aj4[4];
  #pragma unroll
  for (int ti = 0; ti < 4; ti++) {
    int ch = ti * 16 + lm;
    ai4[ti] = att_i[ch]; aj4[ti] = att_j[ch];
    #pragma unroll
    for (int s = 0; s < 2; s++) {
      const float* wp = W_lin + ch * WINW + s * 32 + kb;
      float4 w0 = *(const float4*)wp;
      float4 w1 = *(const float4*)(wp + 4);
      U8 f;
      f.u = make_uint4(pkbf(w0.x, w0.y), pkbf(w0.z, w0.w),
                       pkbf(w1.x, w1.y), pkbf(w1.z, w1.w));
      bfrag[ti][s] = f.b;
    }
  }
  // ---- phase A ----
  #pragma unroll
  for (int tt = 0; tt < 2; tt++) {
    int tile = w * 2 + tt;
    const float* dr = data + ((size_t)b * NNODE + tile * 16 + lm) * WINW + kb;
    f32x4 acc[4];
    #pragma unroll
    for (int ti = 0; ti < 4; ti++) acc[ti] = (f32x4){0.f, 0.f, 0.f, 0.f};
    #pragma unroll
    for (int s = 0; s < 2; s++) {
      float4 d0 = *(const float4*)(dr + s * 32);
      float4 d1 = *(const float4*)(dr + s * 32 + 4);
      U8 af;
      af.u = make_uint4(pkbf(d0.x, d0.y), pkbf(d0.z, d0.w),
                        pkbf(d1.x, d1.y), pkbf(d1.z, d1.w));
      #pragma unroll
      for (int ti = 0; ti < 4; ti++)
        acc[ti] = __builtin_amdgcn_mfma_f32_16x16x32_bf16(af.b, bfrag[ti][s], acc[ti], 0, 0, 0);
    }
    #pragma unroll
    for (int r = 0; r < 4; r++) {
      int nd = tile * 16 + lq * 4 + r;
      float si = 0.f, sj = 0.f;
      #pragma unroll
      for (int ti = 0; ti < 4; ti++) {
        float v = acc[ti][r];
        xl[nd * XLP + ti * 16 + lm] = v;
        si += v * ai4[ti];
        sj += v * aj4[ti];
      }
      si += __shfl_xor(si, 1); si += __shfl_xor(si, 2);
      si += __shfl_xor(si, 4); si += __shfl_xor(si, 8);
      sj += __shfl_xor(sj, 1); sj += __shfl_xor(sj, 2);
      sj += __shfl_xor(sj, 4); sj += __shfl_xor(sj, 8);
      if (lm == 0) { ssi[nd] = si + emb_si[nd]; ssj[nd] = sj + emb_sj[nd]; }
    }
  }
  __syncthreads();
  // ---- phase B: 4 dst nodes per wave-pass; lane = (nd4, l4) ----
  const int nd4 = ln >> 4, l4 = ln & 15;
  float psx = 0.f, psy = 0.f, psz = 0.f, psw = 0.f;
  float qsx = 0.f, qsy = 0.f, qsz = 0.f, qsw = 0.f;
  for (int it = 0; it < 8; it++) {
    int node = w * 32 + it * 4 + nd4;
    const int4* tp = (const int4*)(topk + node * KTOP);
    int4 i0 = tp[0], i1 = tp[1], i2 = tp[2], i3 = tp[3];
    int idx[16] = {i0.x, i0.y, i0.z, i0.w, i1.x, i1.y, i1.z, i1.w,
                   i2.x, i2.y, i2.z, i2.w, i3.x, i3.y, i3.z, i3.w};
    float a = ssi[node] + ssj[idx[l4]];
    a = a > 0.f ? a : NEGS * a;           // leaky_relu
    float mx = a;
    mx = fmaxf(mx, __shfl_xor(mx, 1));
    mx = fmaxf(mx, __shfl_xor(mx, 2));
    mx = fmaxf(mx, __shfl_xor(mx, 4));
    mx = fmaxf(mx, __shfl_xor(mx, 8));
    float e = __expf(a - mx);
    float den = e;
    den += __shfl_xor(den, 1); den += __shfl_xor(den, 2);
    den += __shfl_xor(den, 4); den += __shfl_xor(den, 8);
    ews[w][ln] = e / den;                 // pre-scaled weight (wave-synchronous)
    float4 w0 = *(const float4*)&ews[w][nd4 * 16 + 0];
    float4 w1 = *(const float4*)&ews[w][nd4 * 16 + 4];
    float4 w2 = *(const float4*)&ews[w][nd4 * 16 + 8];
    float4 w3 = *(const float4*)&ews[w][nd4 * 16 + 12];
    float wks[16] = {w0.x, w0.y, w0.z, w0.w, w1.x, w1.y, w1.z, w1.w,
                     w2.x, w2.y, w2.z, w2.w, w3.x, w3.y, w3.z, w3.w};
    float ax = 0.f, ay = 0.f, az = 0.f, aw = 0.f;
    #pragma unroll
    for (int k = 0; k < KTOP; k++) {
      float4 v = *(const float4*)&xl[idx[k] * XLP + l4 * 4];
      ax += wks[k] * v.x; ay += wks[k] * v.y;
      az += wks[k] * v.z; aw += wks[k] * v.w;
    }
    uint2 st = make_uint2(pkbf(ax, ay), pkbf(az, aw));
    *(uint2*)(aggb + (((size_t)b * NNODE + node) << 5) + l4 * 2) = st;
    psx += ax; psy += ay; psz += az; psw += aw;
    qsx += ax * ax; qsy += ay * ay; qsz += az * az; qsw += aw * aw;
  }
  #pragma unroll
  for (int o = 16; o <= 32; o <<= 1) {
    psx += __shfl_xor(psx, o); psy += __shfl_xor(psy, o);
    psz += __shfl_xor(psz, o); psw += __shfl_xor(psw, o);
    qsx += __shfl_xor(qsx, o); qsy += __shfl_xor(qsy, o);
    qsz += __shfl_xor(qsz, o); qsw += __shfl_xor(qsw, o);
  }
  if (ln < 16) {
    float4 a = {psx, psy, psz, psw};
    float4 q = {qsx, qsy, qsz, qsw};
    *(float4*)&redb[w * 128 + ln * 4] = a;
    *(float4*)&redb[w * 128 + 64 + ln * 4] = q;
  }
  __syncthreads();
  if (t < 64) {
    float s = 0.f;
    #pragma unroll
    for (int w16 = 0; w16 < 16; w16++) s += redb[w16 * 128 + t];
    atomicAdd(&gsum1[t], s);
  } else if (t < 128) {
    int e = t - 64;
    float s = 0.f;
    #pragma unroll
    for (int w16 = 0; w16 < 16; w16++) s += redb[w16 * 128 + 64 + e];
    atomicAdd(&gss1[e], s);
  }
}

// ---- K5: BN2 stats over z = relu(bn1(agg))*W_emb; uint4 loads --------------
__global__ __launch_bounds__(256) void k_zstats5(
    const unsigned* __restrict__ aggb, const float* __restrict__ W_emb,
    const float* __restrict__ gsum1, const float* __restrict__ gss1,
    const float* __restrict__ g_bn1, const float* __restrict__ b_bn1,
    float* __restrict__ gsum2, float* __restrict__ gss2) {
  __shared__ float sm[256 * 17];          // pitch 17: conflict-light
  const float invn = 1.f / (float)NTOT;
  const int t = threadIdx.x;
  const int gid = blockIdx.x * 256 + t;
  const int g8 = t & 7;                   // channel octet, fixed across iters
  const int c0 = g8 * 8;
  float a1v[8], c1v[8];
  #pragma unroll
  for (int j = 0; j < 8; j++) {
    int ch = c0 + j;
    float m = gsum1[ch] * invn, vv = gss1[ch] * invn - m * m;
    a1v[j] = g_bn1[ch] * rsqrtf(vv + EPSBN);
    c1v[j] = b_bn1[ch] - m * a1v[j];
  }
  const uint4* ab4 = (const uint4*)aggb;
  const float4* we4 = (const float4*)W_emb;
  float s[8] = {0, 0, 0, 0, 0, 0, 0, 0}, q[8] = {0, 0, 0, 0, 0, 0, 0, 0};
  const int stride = gridDim.x * 256;     // 262144, multiple of 8
  for (int idx = gid; idx < NTOT * 8; idx += stride) {   // 4 iters
    uint4 u = ab4[idx];
    int node = (idx >> 3) & (NNODE - 1);
    float4 w0 = we4[node * 16 + g8 * 2];
    float4 w1 = we4[node * 16 + g8 * 2 + 1];
    float gv[8] = {bf2f(u.x & 0xffffu), bf2f(u.x >> 16),
                   bf2f(u.y & 0xffffu), bf2f(u.y >> 16),
                   bf2f(u.z & 0xffffu), bf2f(u.z >> 16),
                   bf2f(u.w & 0xffffu), bf2f(u.w >> 16)};
    float wv8[8] = {w0.x, w0.y, w0.z, w0.w, w1.x, w1.y, w1.z, w1.w};
    #pragma unroll
    for (int j = 0; j < 8; j++) {
      float z = gv[j] * a1v[j] + c1v[j];
      z = z > 0.f ? z : 0.f;
      z *= wv8[j];
      s[j] += z; q[j] += z * z;
    }
  }
  #pragma unroll
  for (int j = 0; j < 8; j++) { sm[t * 17 + j] = s[j]; sm[t * 17 + 8 + j] = q[j]; }
  __syncthreads();
  if (t < 128) {
    int c = t & 63, st = t >> 6;          // channel, stat
    int col = (c & 7) + 8 * st;
    float tot = 0.f;
    #pragma unroll 8
    for (int k = 0; k < 32; k++) tot += sm[((c >> 3) + 8 * k) * 17 + col];
    atomicAdd(st ? &gss2[c] : &gsum2[c], tot);
  }
}

// ---- K6: MFMA Gram G = h^T h + column sums + h materialization; BN coefs
//      inline from global stats ---------------------------------------------
__global__ __launch_bounds__(256) void k_gram3(
    const unsigned* __restrict__ aggb, const float* __restrict__ W_emb,
    const float* __restrict__ gsum1, const float* __restrict__ gss1,
    const float* __restrict__ g_bn1, const float* __restrict__ b_bn1,
    const float* __restrict__ gsum2, const float* __restrict__ gss2,
    const float* __restrict__ g_bn2, const float* __restrict__ b_bn2,
    float* __restrict__ Gpart, float* __restrict__ hpart,
    unsigned* __restrict__ hb) {
  __shared__ float smem[4 * 4480];   // per-wave region: ht (phase1) / Gbuf (phase2)
  __shared__ float hred[4][64];
  const float invn = 1.f / (float)NTOT;
  const int t = threadIdx.x, wv = t >> 6, ln = t & 63;
  const int lm = ln & 15, lq = ln >> 4;
  const int r4 = ln & 7, ch8 = ln >> 3;
  const int c0 = ch8 * 8;
  float a1v[8], c1v[8], a2v[8], c2v[8];
  #pragma unroll
  for (int j = 0; j < 8; j++) {
    int ch = c0 + j;
    float m = gsum1[ch] * invn, vv = gss1[ch] * invn - m * m;
    a1v[j] = g_bn1[ch] * rsqrtf(vv + EPSBN); c1v[j] = b_bn1[ch] - m * a1v[j];
    float m2 = gsum2[ch] * invn, v2 = gss2[ch] * invn - m2 * m2;
    a2v[j] = g_bn2[ch] * rsqrtf(v2 + EPSBN); c2v[j] = b_bn2[ch] - m2 * a2v[j];
  }
  unsigned* ht = (unsigned*)(smem + wv * 4480);
  bf16x8 ones;
  #pragma unroll
  for (int j = 0; j < 8; j++) ones[j] = (short)0x3F80;
  f32x4 acc[4][4];
  f32x4 accS[4];
  #pragma unroll
  for (int i = 0; i < 4; i++) {
    accS[i] = (f32x4){0.f, 0.f, 0.f, 0.f};
    #pragma unroll
    for (int j = 0; j < 4; j++) acc[i][j] = (f32x4){0.f, 0.f, 0.f, 0.f};
  }
  const uint4* ab4 = (const uint4*)aggb;
  uint4* hb4 = (uint4*)hb;
  const float4* we4 = (const float4*)W_emb;
  const int blockrow = blockIdx.x * 256;
  #pragma unroll
  for (int ck = 0; ck < 2; ck++) {
    int k0 = blockrow + wv * 64 + ck * 32;
    #pragma unroll
    for (int rr2 = 0; rr2 < 2; rr2++) {
      float h2[2][8];
      #pragma unroll
      for (int rh = 0; rh < 2; rh++) {
        int lr = r4 * 4 + rr2 * 2 + rh;
        int row = k0 + lr;
        int node = row & (NNODE - 1);
        uint4 u = ab4[(size_t)row * 8 + ch8];
        float4 w0 = we4[node * 16 + ch8 * 2];
        float4 w1 = we4[node * 16 + ch8 * 2 + 1];
        float gv[8] = {bf2f(u.x & 0xffffu), bf2f(u.x >> 16),
                       bf2f(u.y & 0xffffu), bf2f(u.y >> 16),
                       bf2f(u.z & 0xffffu), bf2f(u.z >> 16),
                       bf2f(u.w & 0xffffu), bf2f(u.w >> 16)};
        float wv8[8] = {w0.x, w0.y, w0.z, w0.w, w1.x, w1.y, w1.z, w1.w};
        #pragma unroll
        for (int j = 0; j < 8; j++) {
          float z = gv[j] * a1v[j] + c1v[j];
          z = z > 0.f ? z : 0.f;
          z *= wv8[j];
          float hh = z * a2v[j] + c2v[j];
          hh = hh > 0.f ? hh : 0.f;
          h2[rh][j] = hh;
        }
        hb4[(size_t)row * 8 + ch8] =
            make_uint4(pkbf(h2[rh][0], h2[rh][1]), pkbf(h2[rh][2], h2[rh][3]),
                       pkbf(h2[rh][4], h2[rh][5]), pkbf(h2[rh][6], h2[rh][7]));
      }
      #pragma unroll
      for (int cc = 0; cc < 8; cc++) {
        int ch = c0 + cc;
        int base = ch * 20 + ((ch >> 3) & 3) * 4;   // swizzled base, 16B-aligned
        ht[base + r4 * 2 + rr2] = pkbf(h2[0][cc], h2[1][cc]);
      }
    }
    bf16x8 frag[4];
    #pragma unroll
    for (int i = 0; i < 4; i++) {
      int ch = i * 16 + lm;
      int base = ch * 20 + ((ch >> 3) & 3) * 4;
      frag[i] = *(const bf16x8*)(ht + base + lq * 4);
    }
    #pragma unroll
    for (int i = 0; i < 4; i++) {
      #pragma unroll
      for (int j = 0; j < 4; j++)
        acc[i][j] = __builtin_amdgcn_mfma_f32_16x16x32_bf16(frag[i], frag[j], acc[i][j], 0, 0, 0);
      accS[i] = __builtin_amdgcn_mfma_f32_16x16x32_bf16(frag[i], ones, accS[i], 0, 0, 0);
    }
  }
  __syncthreads();   // all waves done with ht before Gbuf overwrite
  float* Gb = smem + wv * 4480;    // col-major, pitch 68 (G symmetric)
  #pragma unroll
  for (int i = 0; i < 4; i++) {
    #pragma unroll
    for (int j = 0; j < 4; j++) {
      float4 vv = {acc[i][j][0], acc[i][j][1], acc[i][j][2], acc[i][j][3]};
      *(float4*)(Gb + (j * 16 + lm) * 68 + i * 16 + lq * 4) = vv;
    }
    if (lm == 0) {
      float4 sv = {accS[i][0], accS[i][1], accS[i][2], accS[i][3]};
      *(float4*)&hred[wv][i * 16 + lq * 4] = sv;
    }
  }
  __syncthreads();
  for (int k = t; k < 4096; k += 256) {
    int col = k >> 6, row = k & 63;
    int o = col * 68 + row;
    Gpart[(size_t)blockIdx.x * 4096 + k] =
        smem[o] + smem[4480 + o] + smem[2 * 4480 + o] + smem[3 * 4480 + o];
  }
  if (t < 64)
    hpart[(size_t)blockIdx.x * 64 + t] =
        hred[0][t] + hred[1][t] + hred[2][t] + hred[3][t];
}

// ---- K6b: reduce Gpart/hpart — wide (16-deep sums, 32-way atomic finish) ---
__global__ __launch_bounds__(256) void k_gred(const float* __restrict__ Gpart,
                                              const float* __restrict__ hpart,
                                              float* __restrict__ G,
                                              float* __restrict__ hsum) {
  int wi = blockIdx.x * 256 + threadIdx.x;   // grid 514*256
  if (wi < 131072) {
    int e = wi & 4095, seg = wi >> 12;       // 32 segments of 16 blocks
    float s = 0.f;
    #pragma unroll
    for (int k = 0; k < 16; k++) s += Gpart[(size_t)(seg * 16 + k) * 4096 + e];
    atomicAdd(&G[e], s);
  } else if (wi < 131072 + 512) {
    int wi2 = wi - 131072;
    int e = wi2 & 63, seg = wi2 >> 6;        // 8 segments of 64 blocks
    float s = 0.f;
    #pragma unroll 8
    for (int k = 0; k < 64; k++) s += hpart[(size_t)(seg * 64 + k) * 64 + e];
    atomicAdd(&hsum[e], s);
  }
}

// ---- K6c: BN3 coefs from Gram: per channel c quadform W1c^T G W1c ----------
__global__ __launch_bounds__(64) void k_fin3q(
    const float* __restrict__ G, const float* __restrict__ hsum,
    const float* __restrict__ W1, const float* __restrict__ b1,
    const float* __restrict__ g3, const float* __restrict__ b3,
    float* __restrict__ a3, float* __restrict__ c3) {
  __shared__ float sw[64];
  int c = blockIdx.x, i = threadIdx.x;
  float w1i = W1[c * 64 + i];
  sw[i] = w1i;
  __syncthreads();
  float gw = 0.f;
  #pragma unroll
  for (int j = 0; j < 64; j++) gw += G[j * 64 + i] * sw[j];   // G symmetric
  float t1 = w1i * gw;       // -> quadform
  float t2 = w1i * hsum[i];  // -> sum of dots
  for (int o = 32; o > 0; o >>= 1) { t1 += __shfl_xor(t1, o); t2 += __shfl_xor(t2, o); }
  if (i == 0) {
    float b1c = b1[c];
    const float fn = (float)NTOT, invn = 1.f / fn;
    float sum3 = t2 + fn * b1c;
    float ss3  = t1 + 2.f * b1c * t2 + fn * b1c * b1c;
    float m = sum3 * invn;
    float v = ss3 * invn - m * m;
    float aa = g3[c] * rsqrtf(v + EPSBN);
    a3[c] = aa;
    c3[c] = b3[c] - m * aa;
  }
}

// ---- K7: output GEMM — barrier-free, LDS-free; atomicAdd combine -----------
__global__ __launch_bounds__(512) void k_gout3(
    const unsigned* __restrict__ hb, const float* __restrict__ W1,
    const float* __restrict__ b1, const float* __restrict__ a3,
    const float* __restrict__ c3, const float* __restrict__ W2,
    const float* __restrict__ b2, float* __restrict__ out) {
  const int t = threadIdx.x, wv = t >> 6, ln = t & 63;
  const int lm = ln & 15, lq = ln >> 4, kb = lq * 8;
  bf16x8 bfrag[4][2];
  float b1c[4], a3c[4], c3c[4], w2c[4];
  #pragma unroll
  for (int nt = 0; nt < 4; nt++) {
    int col = wv * 64 + nt * 16 + lm;
    b1c[nt] = b1[col]; a3c[nt] = a3[col]; c3c[nt] = c3[col]; w2c[nt] = W2[col];
    #pragma unroll
    for (int s = 0; s < 2; s++) {
      const float* wp = W1 + col * EMBD + s * 32 + kb;
      float4 w0 = *(const float4*)wp;
      float4 w1 = *(const float4*)(wp + 4);
      U8 f;
      f.u = make_uint4(pkbf(w0.x, w0.y), pkbf(w0.z, w0.w),
                       pkbf(w1.x, w1.y), pkbf(w1.z, w1.w));
      bfrag[nt][s] = f.b;
    }
  }
  float b2v = b2[0];
  const uint4* h4 = (const uint4*)hb;
  for (int tile = blockIdx.x; tile < NTOT / 16; tile += gridDim.x) {
    int rowbase = tile * 16;
    U8 ua, ub;
    ua.u = h4[(size_t)(rowbase + lm) * 8 + lq];       // k-half 0
    ub.u = h4[(size_t)(rowbase + lm) * 8 + 4 + lq];   // k-half 1
    f32x4 acc[4];
    #pragma unroll
    for (int nt = 0; nt < 4; nt++) acc[nt] = (f32x4){0.f, 0.f, 0.f, 0.f};
    #pragma unroll
    for (int nt = 0; nt < 4; nt++)
      acc[nt] = __builtin_amdgcn_mfma_f32_16x16x32_bf16(ua.b, bfrag[nt][0], acc[nt], 0, 0, 0);
    #pragma unroll
    for (int nt = 0; nt < 4; nt++)
      acc[nt] = __builtin_amdgcn_mfma_f32_16x16x32_bf16(ub.b, bfrag[nt][1], acc[nt], 0, 0, 0);
    #pragma unroll
    for (int r = 0; r < 4; r++) {
      float p = 0.f;
      #pragma unroll
      for (int nt = 0; nt < 4; nt++) {
        float z2 = acc[nt][r] + b1c[nt];
        float y = z2 * a3c[nt] + c3c[nt];
        y = y > 0.f ? y : 0.f;
        p += y * w2c[nt];
      }
      p += __shfl_xor(p, 1); p += __shfl_xor(p, 2);
      p += __shfl_xor(p, 4); p += __shfl_xor(p, 8);
      if (lm == 0) {
        if (wv == 0) p += b2v;
        atomicAdd(&out[rowbase + lq * 4 + r], p);
      }
    }
  }
}

extern "C" void kernel_launch(void* const* d_in, const int* in_sizes, int n_in,
                              void* d_out, int out_size, void* d_ws, size_t ws_size,
                              hipStream_t stream) {
  const float* data     = (const float*)d_in[0];
  // d_in[1] org_edge_index: unused by forward
  const float* W_emb    = (const float*)d_in[2];
  const float* W_lin    = (const float*)d_in[3];
  const float* att_i    = (const float*)d_in[4];
  const float* att_j    = (const float*)d_in[5];
  const float* att_em_i = (const float*)d_in[6];
  const float* att_em_j = (const float*)d_in[7];
  // d_in[8] b_gnn: cancels exactly inside training-mode BN1
  const float* g_bn1    = (const float*)d_in[9];
  const float* b_bn1    = (const float*)d_in[10];
  const float* g_bn2    = (const float*)d_in[11];
  const float* b_bn2    = (const float*)d_in[12];
  const float* W1       = (const float*)d_in[13];
  const float* b1       = (const float*)d_in[14];
  const float* g_bn3    = (const float*)d_in[15];
  const float* b_bn3    = (const float*)d_in[16];
  const float* W2       = (const float*)d_in[17];
  const float* b2       = (const float*)d_in[18];
  float* out = (float*)d_out;

  char* p = (char*)d_ws;
  auto alloc = [&](size_t bytes) {
    void* r = (void*)p;
    p += (bytes + 255) & ~(size_t)255;
    return r;
  };
  unsigned* aggb  = (unsigned*)alloc((size_t)NTOT * EMBD * 2);   // 16.8 MB bf16
  unsigned* hb    = (unsigned*)alloc((size_t)NTOT * EMBD * 2);   // 16.8 MB bf16
  float*    Gpart = (float*)alloc((size_t)512 * 4096 * 4);       // 8.4 MB
  float*    hpart = (float*)alloc((size_t)512 * 64 * 4);
  float*    nw    = (float*)alloc((size_t)NNODE * EMBD * 4);
  float*    emb_si = (float*)alloc(NNODE * 4);
  float*    emb_sj = (float*)alloc(NNODE * 4);
  int*      topk   = (int*)alloc(NNODE * KTOP * 4);
  float*    stats  = (float*)alloc(4416 * 4);   // gsum1,gss1,gsum2,gss2,G,hsum
  float*    coefs  = (float*)alloc(1280 * 4);   // a3,c3

  float* gsum1 = stats;       float* gss1 = stats + 64;
  float* gsum2 = stats + 128; float* gss2 = stats + 192;
  float* G     = stats + 256; float* hsum = stats + 4352;
  float* a3 = coefs;          float* c3 = coefs + 512;

  k_prep<<<NNODE, 64, 0, stream>>>(W_emb, att_em_i, att_em_j, nw, emb_si,
                                   emb_sj, stats);
  k_topk<<<NNODE, 256, 0, stream>>>(nw, topk, out);
  k_fuse5<<<BATCH, 1024, 0, stream>>>(data, W_lin, att_i, att_j, emb_si, emb_sj,
                                      topk, aggb, gsum1, gss1);
  k_zstats5<<<1024, 256, 0, stream>>>(aggb, W_emb, gsum1, gss1, g_bn1, b_bn1,
                                      gsum2, gss2);
  k_gram3<<<512, 256, 0, stream>>>(aggb, W_emb, gsum1, gss1, g_bn1, b_bn1,
                                   gsum2, gss2, g_bn2, b_bn2, Gpart, hpart, hb);
  k_gred<<<514, 256, 0, stream>>>(Gpart, hpart, G, hsum);
  k_fin3q<<<CIN, 64, 0, stream>>>(G, hsum, W1, b1, g_bn3, b_bn3, a3, c3);
  k_gout3<<<512, 512, 0, stream>>>(hb, W1, b1, a3, c3, W2, b2, out);
}